// Round 1
// baseline (432.070 us; speedup 1.0000x reference)
//
#include <hip/hip_runtime.h>

#define EPSN 1e-12f
#define SCALE_F 0.044194173824159216f  // 512^-0.5

typedef __bf16 bf16x8 __attribute__((ext_vector_type(8)));
typedef float  f32x4  __attribute__((ext_vector_type(4)));

// ---------------- prep: WqT/WkT bf16 [d][c] = W[c][d] ----------------
__global__ __launch_bounds__(256) void k_prep_t(const float* __restrict__ Wq,
                                                const float* __restrict__ Wk,
                                                __bf16* __restrict__ WqT,
                                                __bf16* __restrict__ WkT) {
  int idx = blockIdx.x * 256 + threadIdx.x;   // 262144 total
  int d = idx >> 9, c = idx & 511;
  WqT[idx] = (__bf16)Wq[c * 512 + d];
  WkT[idx] = (__bf16)Wk[c * 512 + d];
}

// ---- prep: WcT[d][kk]: kk<512 -> (Wp@Wf)[kk][d]; kk>=512 -> Wf[kk-512][d]. bpf[d]=bp@Wf+bf
__global__ __launch_bounds__(512) void k_prep_w(const float* __restrict__ Wp,
                                                const float* __restrict__ Wf,
                                                const float* __restrict__ bp,
                                                const float* __restrict__ bfv,
                                                __bf16* __restrict__ WcT,
                                                float* __restrict__ bpf) {
  int kk = blockIdx.x;   // 512
  int d  = threadIdx.x;  // 512
  float acc = 0.f;
  for (int c = 0; c < 512; ++c) acc = fmaf(Wp[kk * 512 + c], Wf[c * 512 + d], acc);
  WcT[(size_t)d * 1024 + kk]       = (__bf16)acc;
  WcT[(size_t)d * 1024 + 512 + kk] = (__bf16)Wf[kk * 512 + d];
  if (kk == 0) {
    float a2 = 0.f;
    for (int c = 0; c < 512; ++c) a2 = fmaf(bp[c], Wf[c * 512 + d], a2);
    bpf[d] = a2 + bfv[d];
  }
}

// ---------------- fused Q/K GEMM + bias + row l2norm + g ----------------
// tile: 64 tokens x 512 d, K=512 (BK=32). 8 waves, wave w owns cols [w*64, w*64+64).
// A (x^T tile) staged in LDS (f32->bf16 transpose); B fragments gathered directly
// from WqT/WkT (L2-resident, 16 lines x 64B fully consumed per b128 gather).
__global__ __launch_bounds__(512) void k_qk(const float* __restrict__ x,
                                            const __bf16* __restrict__ WqT,
                                            const __bf16* __restrict__ WkT,
                                            const float* __restrict__ bq,
                                            const float* __restrict__ bk,
                                            const float* __restrict__ wg,
                                            __bf16* __restrict__ Qn,
                                            __bf16* __restrict__ Kn,
                                            float* __restrict__ g) {
  __shared__ __bf16 As[64][40];                    // 32 k + 8 pad -> 20-word stride, 2-way max
  __shared__ float redQ[8][64], redK[8][64], redG[8][64];
  __shared__ float invq[64], invk[64];
  const int t = threadIdx.x;
  const int lane = t & 63, w = t >> 6;
  const int li = lane & 15, lq = lane >> 4;
  const int n0 = blockIdx.x * 64;
  const int b  = blockIdx.y;
  const int sn = t & 63;          // staging row (token)
  const int sc = t >> 6;          // staging col base (c)
  f32x4 accQ[4][4] = {}, accK[4][4] = {};
  for (int ks = 0; ks < 16; ++ks) {
    const int c0 = ks * 32;
    // stage A: As[n][c] = bf16(x[b][c0+c][n0+n]) ; transpose during staging
    #pragma unroll
    for (int p = 0; p < 4; ++p) {
      int c = sc + p * 8;
      float v = 0.f;
      if (n0 + sn < 784) v = x[((size_t)b * 512 + c0 + c) * 784 + n0 + sn];
      As[sn][c] = (__bf16)v;
    }
    __syncthreads();
    bf16x8 af[4];
    #pragma unroll
    for (int rb = 0; rb < 4; ++rb)
      af[rb] = *(const bf16x8*)&As[rb * 16 + li][lq * 8];
    #pragma unroll
    for (int cb = 0; cb < 4; ++cb) {
      const int drow = w * 64 + cb * 16 + li;
      bf16x8 bqf = *(const bf16x8*)(WqT + (size_t)drow * 512 + c0 + lq * 8);
      bf16x8 bkf = *(const bf16x8*)(WkT + (size_t)drow * 512 + c0 + lq * 8);
      #pragma unroll
      for (int rb = 0; rb < 4; ++rb) {
        accQ[rb][cb] = __builtin_amdgcn_mfma_f32_16x16x32_bf16(af[rb], bqf, accQ[rb][cb], 0, 0, 0);
        accK[rb][cb] = __builtin_amdgcn_mfma_f32_16x16x32_bf16(af[rb], bkf, accK[rb][cb], 0, 0, 0);
      }
    }
    __syncthreads();
  }
  // epilogue: + bias, row sumsq / g-dot reduce (deterministic), normalize, store bf16
  float bqv[4], bkv[4], wgv[4];
  #pragma unroll
  for (int cb = 0; cb < 4; ++cb) {
    int col = w * 64 + cb * 16 + li;
    bqv[cb] = bq[col]; bkv[cb] = bk[col]; wgv[cb] = wg[col];
  }
  #pragma unroll
  for (int rb = 0; rb < 4; ++rb)
    #pragma unroll
    for (int cb = 0; cb < 4; ++cb)
      #pragma unroll
      for (int j = 0; j < 4; ++j) {
        accQ[rb][cb][j] += bqv[cb];
        accK[rb][cb][j] += bkv[cb];
      }
  #pragma unroll
  for (int rb = 0; rb < 4; ++rb)
    #pragma unroll
    for (int j = 0; j < 4; ++j) {
      float sq = 0.f, sk = 0.f, sg = 0.f;
      #pragma unroll
      for (int cb = 0; cb < 4; ++cb) {
        float vq = accQ[rb][cb][j], vk = accK[rb][cb][j];
        sq = fmaf(vq, vq, sq); sk = fmaf(vk, vk, sk); sg = fmaf(vq, wgv[cb], sg);
      }
      sq += __shfl_xor(sq, 1); sq += __shfl_xor(sq, 2); sq += __shfl_xor(sq, 4); sq += __shfl_xor(sq, 8);
      sk += __shfl_xor(sk, 1); sk += __shfl_xor(sk, 2); sk += __shfl_xor(sk, 4); sk += __shfl_xor(sk, 8);
      sg += __shfl_xor(sg, 1); sg += __shfl_xor(sg, 2); sg += __shfl_xor(sg, 4); sg += __shfl_xor(sg, 8);
      if (li == 0) {
        int row = rb * 16 + lq * 4 + j;
        redQ[w][row] = sq; redK[w][row] = sk; redG[w][row] = sg;
      }
    }
  __syncthreads();
  if (t < 64) {
    float sq = 0.f, sk = 0.f, sg = 0.f;
    #pragma unroll
    for (int wv = 0; wv < 8; ++wv) { sq += redQ[wv][t]; sk += redK[wv][t]; sg += redG[wv][t]; }
    float iq = 1.f / fmaxf(sqrtf(sq), EPSN);
    float ik = 1.f / fmaxf(sqrtf(sk), EPSN);
    invq[t] = iq; invk[t] = ik;
    if (n0 + t < 784) g[(size_t)b * 784 + n0 + t] = sg * iq;
  }
  __syncthreads();
  #pragma unroll
  for (int rb = 0; rb < 4; ++rb)
    #pragma unroll
    for (int j = 0; j < 4; ++j) {
      int row = rb * 16 + lq * 4 + j;
      if (n0 + row < 784) {
        float iq = invq[row], ik = invk[row];
        size_t base = ((size_t)b * 784 + n0 + row) * 512 + w * 64 + li;
        #pragma unroll
        for (int cb = 0; cb < 4; ++cb) {
          Qn[base + cb * 16] = (__bf16)(accQ[rb][cb][j] * iq);
          Kn[base + cb * 16] = (__bf16)(accK[rb][cb][j] * ik);
        }
      }
    }
}

// ---------------- per-batch: ||g||, ctx[d] = alpha * sum_n g[n]*Qn[n,d] ----------------
__global__ __launch_bounds__(512) void k_ctx(const __bf16* __restrict__ Qn,
                                             const float* __restrict__ g,
                                             float* __restrict__ ctx) {
  const int b = blockIdx.x, t = threadIdx.x;
  __shared__ float wred[8];
  const float* gb = g + (size_t)b * 784;
  float s = 0.f;
  for (int n = t; n < 784; n += 512) { float v = gb[n]; s = fmaf(v, v, s); }
  s += __shfl_xor(s, 1);  s += __shfl_xor(s, 2);  s += __shfl_xor(s, 4);
  s += __shfl_xor(s, 8);  s += __shfl_xor(s, 16); s += __shfl_xor(s, 32);
  if ((t & 63) == 0) wred[t >> 6] = s;
  __syncthreads();
  float tot = 0.f;
  #pragma unroll
  for (int i = 0; i < 8; ++i) tot += wred[i];
  float alpha = SCALE_F / fmaxf(sqrtf(tot) * SCALE_F, EPSN);
  const __bf16* qb = Qn + (size_t)b * 784 * 512;
  float a0 = 0.f, a1 = 0.f, a2 = 0.f, a3 = 0.f;
  for (int n = 0; n < 784; n += 4) {
    a0 = fmaf(gb[n],     (float)qb[(size_t)n * 512 + t],       a0);
    a1 = fmaf(gb[n + 1], (float)qb[(size_t)(n + 1) * 512 + t], a1);
    a2 = fmaf(gb[n + 2], (float)qb[(size_t)(n + 2) * 512 + t], a2);
    a3 = fmaf(gb[n + 3], (float)qb[(size_t)(n + 3) * 512 + t], a3);
  }
  ctx[(size_t)b * 512 + t] = alpha * ((a0 + a1) + (a2 + a3));
}

// ---------------- final GEMM: out[n,d] = [ctx*Kn | Qn] @ [Wpf;Wf] + bpf, write out[b,d,n] ----------------
// tile 64(n) x 256(d), K=1024 (BK=64), 8 waves in 2x4 grid (wave: 32 rows x 64 cols).
__global__ __launch_bounds__(512) void k_out(const __bf16* __restrict__ Qn,
                                             const __bf16* __restrict__ Kn,
                                             const float* __restrict__ ctx,
                                             const __bf16* __restrict__ WcT,
                                             const float* __restrict__ bpf,
                                             float* __restrict__ out) {
  __shared__ __align__(16) char smem[64 * 72 * 2 + 256 * 72 * 2];   // 46080 B
  __bf16 (*As)[72] = (__bf16(*)[72])smem;
  __bf16 (*Bs)[72] = (__bf16(*)[72])(smem + 64 * 72 * 2);
  float  (*Cs)[65] = (float(*)[65])smem;   // epilogue overlay, 64x65x4 = 16640 B
  const int t = threadIdx.x;
  const int lane = t & 63, w = t >> 6;
  const int li = lane & 15, lq = lane >> 4;
  const int wr = w >> 2, wc = w & 3;
  const int n0 = blockIdx.x * 64;
  const int d0 = blockIdx.y * 256;
  const int b  = blockIdx.z;
  const int arow = t >> 3, asg = t & 7;
  f32x4 acc[2][4] = {};
  for (int ks = 0; ks < 16; ++ks) {
    const int k0 = ks * 64;
    { // stage A (ctx fold on the Kn half)
      int kk = k0 + asg * 8;
      int n = n0 + arow;
      bf16x8 v = {};
      if (kk < 512) {
        if (n < 784) v = *(const bf16x8*)(Kn + ((size_t)b * 784 + n) * 512 + kk);
        const float* cp = ctx + b * 512 + kk;
        bf16x8 r;
        #pragma unroll
        for (int j = 0; j < 8; ++j) r[j] = (__bf16)((float)v[j] * cp[j]);
        *(bf16x8*)&As[arow][asg * 8] = r;
      } else {
        if (n < 784) v = *(const bf16x8*)(Qn + ((size_t)b * 784 + n) * 512 + kk - 512);
        *(bf16x8*)&As[arow][asg * 8] = v;
      }
    }
    // stage B
    #pragma unroll
    for (int p = 0; p < 4; ++p) {
      int d = (t >> 3) + p * 64;
      *(bf16x8*)&Bs[d][asg * 8] = *(const bf16x8*)(WcT + (size_t)(d0 + d) * 1024 + k0 + asg * 8);
    }
    __syncthreads();
    bf16x8 af[2][2], bfr[4][2];
    #pragma unroll
    for (int rb = 0; rb < 2; ++rb)
      #pragma unroll
      for (int kf = 0; kf < 2; ++kf)
        af[rb][kf] = *(const bf16x8*)&As[wr * 32 + rb * 16 + li][kf * 32 + lq * 8];
    #pragma unroll
    for (int cb = 0; cb < 4; ++cb)
      #pragma unroll
      for (int kf = 0; kf < 2; ++kf)
        bfr[cb][kf] = *(const bf16x8*)&Bs[wc * 64 + cb * 16 + li][kf * 32 + lq * 8];
    #pragma unroll
    for (int kf = 0; kf < 2; ++kf)
      #pragma unroll
      for (int rb = 0; rb < 2; ++rb)
        #pragma unroll
        for (int cb = 0; cb < 4; ++cb)
          acc[rb][cb] = __builtin_amdgcn_mfma_f32_16x16x32_bf16(af[rb][kf], bfr[cb][kf], acc[rb][cb], 0, 0, 0);
    __syncthreads();
  }
  // epilogue: LDS-transpose 64-col chunks -> coalesced [b,d,n] writes
  for (int ch = 0; ch < 4; ++ch) {
    if (wc == ch) {
      #pragma unroll
      for (int cb = 0; cb < 4; ++cb) {
        int colL = cb * 16 + li;
        float bias = bpf[d0 + ch * 64 + colL];
        #pragma unroll
        for (int rb = 0; rb < 2; ++rb)
          #pragma unroll
          for (int j = 0; j < 4; ++j)
            Cs[colL][wr * 32 + rb * 16 + lq * 4 + j] = acc[rb][cb][j] + bias;
      }
    }
    __syncthreads();
    {
      int n = t & 63, dl = t >> 6;
      if (n0 + n < 784) {
        #pragma unroll
        for (int p = 0; p < 8; ++p)
          out[((size_t)b * 512 + d0 + ch * 64 + dl + p * 8) * 784 + n0 + n] = Cs[dl + p * 8][n];
      }
    }
    __syncthreads();
  }
}

extern "C" void kernel_launch(void* const* d_in, const int* in_sizes, int n_in,
                              void* d_out, int out_size, void* d_ws, size_t ws_size,
                              hipStream_t stream) {
  const float* x   = (const float*)d_in[0];
  const float* Wq  = (const float*)d_in[1];
  const float* bq  = (const float*)d_in[2];
  const float* Wk  = (const float*)d_in[3];
  const float* bk  = (const float*)d_in[4];
  const float* wg  = (const float*)d_in[5];
  const float* Wp  = (const float*)d_in[6];
  const float* bp  = (const float*)d_in[7];
  const float* Wf  = (const float*)d_in[8];
  const float* bfv = (const float*)d_in[9];
  float* out = (float*)d_out;
  char* ws = (char*)d_ws;

  const size_t SZQN = (size_t)64 * 784 * 512 * 2;     // 51,380,224 B
  __bf16* Qn   = (__bf16*)(ws);
  __bf16* Kn   = (__bf16*)(ws + SZQN);
  __bf16* WqT  = (__bf16*)(ws + 2 * SZQN);
  __bf16* WkT  = (__bf16*)(ws + 2 * SZQN + 524288);
  __bf16* WcT  = (__bf16*)(ws + 2 * SZQN + 2 * 524288);
  float*  gbuf = (float*) (ws + 2 * SZQN + 2 * 524288 + 1048576);
  float*  ctx  = (float*) (ws + 2 * SZQN + 2 * 524288 + 1048576 + 200704);
  float*  bpf  = (float*) (ws + 2 * SZQN + 2 * 524288 + 1048576 + 200704 + 131072);
  // total workspace: ~105.2 MB

  k_prep_t<<<dim3(1024), dim3(256), 0, stream>>>(Wq, Wk, WqT, WkT);
  k_prep_w<<<dim3(512),  dim3(512), 0, stream>>>(Wp, Wf, bp, bfv, WcT, bpf);
  k_qk   <<<dim3(13, 64),    dim3(512), 0, stream>>>(x, WqT, WkT, bq, bk, wg, Qn, Kn, gbuf);
  k_ctx  <<<dim3(64),        dim3(512), 0, stream>>>(Qn, gbuf, ctx);
  k_out  <<<dim3(13, 2, 64), dim3(512), 0, stream>>>(Qn, Kn, ctx, WcT, bpf, out);
}